// Round 8
// baseline (113.877 us; speedup 1.0000x reference)
//
#include <hip/hip_runtime.h>
#include <hip/hip_bf16.h>
#include <cfloat>
#include <cmath>

namespace {
constexpr int NB = 2;     // batch
constexpr int NN = 64;    // user inputs
constexpr int NC = 256;   // feature channels
constexpr int NK = 10;    // classes
constexpr float ALPHA = -1.0f / 18.0f;   // -0.5/sigma^2, sigma=3
constexpr int TMPL_FLOATS = 3 * NB * NC * NN;  // 98304 floats = 384 KiB
} // namespace

// Wave-uniform fp32-vs-bf16 sniff on x0's first 2KB. fp32 low halves are
// ~uniform bits -> bf16-exp>=137 (|v|>=1024/inf/NaN) appears w.p. ~1;
// bf16 N(0,1) never has exp>=137.
__device__ __forceinline__ bool sniff_f32(const void* x0) {
  const ushort4 v = ((const ushort4*)x0)[threadIdx.x & 63];
  bool bad = (((v.x >> 7) & 0xFF) >= 137) | (((v.y >> 7) & 0xFF) >= 137) |
             (((v.z >> 7) & 0xFF) >= 137) | (((v.w >> 7) & 0xFF) >= 137);
  return __ballot(bad) != 0ULL;
}

// load float input element i, runtime dtype (wave-uniform f32 flag)
__device__ __forceinline__ float ldf(const void* p, size_t i, bool f32) {
  return f32 ? ((const float*)p)[i]
             : __bfloat162float(((const __hip_bfloat16*)p)[i]);
}

// ---------------------------------------------------------------------------
// Kernel 1 (unchanged; ~4us, never in top-5): per (level,b,n) template
// tmpl[c] = sum_p h[p]*feat[c,p], thread = channel, per-thread window loop.
// Output [lvl][b][c][n], n contiguous.
// ---------------------------------------------------------------------------
__global__ __launch_bounds__(256) void tmpl_kernel(
    const void* __restrict__ x0, const void* __restrict__ x1,
    const void* __restrict__ x2, const void* __restrict__ centers,
    const int* __restrict__ idxp, const int* __restrict__ labels,
    float* __restrict__ tmpl_t) {
  const bool f32 = sniff_f32(x0);
  const int bx  = blockIdx.x;          // 3*NB*NN = 384 blocks
  const int lvl = bx >> 7;
  const int b   = (bx >> 6) & 1;
  const int n   = bx & 63;
  const int W   = 64 >> lvl;           // 64,32,16
  const int HW  = W * W;
  const float s = (float)(8 << lvl);   // nearest-resize stride
  const void* feat = (lvl == 0) ? x0 : (lvl == 1) ? x1 : x2;

  __shared__ float ex[64], ey[64];
  __shared__ float sh_inv;
  __shared__ int   sh_win[4];

  const int t = threadIdx.x;
  const float cx = ldf(centers, (size_t)(b * NN + n) * 2 + 0, f32);
  const float cy = ldf(centers, (size_t)(b * NN + n) * 2 + 1, f32);

  if (t < W) {
    const float dx = (float)t * s + 0.5f - cx;
    const float dy = (float)t * s + 0.5f - cy;
    ex[t] = expf(ALPHA * dx * dx);
    ey[t] = expf(ALPHA * dy * dy);
  }
  __syncthreads();

  if (t == 0) {
    const bool i64 = (labels[1] == 0);            // int64 hedge
    const int  m   = b * NN + n;
    const int  iv  = i64 ? idxp[2 * m] : idxp[m];
    float Sx = 0.f, Sy = 0.f;
    for (int i = 0; i < W; ++i) { Sx += ex[i]; Sy += ey[i]; }
    sh_inv = (iv != -1) ? 1.0f / (Sx * Sy + 1e-8f) : 0.0f;
    int cs = (int)floorf((cx - 0.5f) / s + 0.5f); cs = min(max(cs, 0), W - 1);
    int rs = (int)floorf((cy - 0.5f) / s + 0.5f); rs = min(max(rs, 0), W - 1);
    const float tx = ex[cs] * 1e-7f, ty = ey[rs] * 1e-7f;
    int clo = cs, chi = cs, rlo = rs, rhi = rs;
    while (clo > 0     && ex[clo - 1] >= tx) --clo;
    while (chi < W - 1 && ex[chi + 1] >= tx) ++chi;
    while (rlo > 0     && ey[rlo - 1] >= ty) --rlo;
    while (rhi < W - 1 && ey[rhi + 1] >= ty) ++rhi;
    sh_win[0] = clo; sh_win[1] = chi; sh_win[2] = rlo; sh_win[3] = rhi;
  }
  __syncthreads();

  const float inv = sh_inv;
  const int clo = sh_win[0], chi = sh_win[1], rlo = sh_win[2], rhi = sh_win[3];
  const size_t cbase = (size_t)(b * NC + t) * HW;   // t = channel
  float acc = 0.f;
  for (int r = rlo; r <= rhi; ++r) {
    float rowa = 0.f;
    for (int c = clo; c <= chi; ++c)
      rowa += ex[c] * ldf(feat, cbase + r * W + c, f32);
    acc += ey[r] * rowa;
  }
  tmpl_t[(((size_t)lvl * NB + b) * NC + t) * NN + n] = acc * inv;
}

// ---------------------------------------------------------------------------
// Kernel 2 (v6): block = 64-pixel tile, 1024 threads = 16 waves =
// 4 n-chunks x 4 c-quarters. R7 evidence: LDS-broadcast tmpl reads are
// issue-bound (4096 ds_read_b128/block ~= 19us). v6 moves tmpl to the SCALAR
// pipe: wave-uniform global reads (compiler emits s_load_dwordx16 — proven in
// R5 by VGPR=24/SGPR=80) with an explicit 4-deep rotating buffer (literal
// stage index) so each refill has ~48 FMAs x 2.6 waves/SIMD of latency cover.
// LDS only for partials/class-max. 168 blocks.
// ---------------------------------------------------------------------------
__global__ __launch_bounds__(1024, 1) void cor_kernel(
    const void* __restrict__ x0, const void* __restrict__ x1,
    const void* __restrict__ x2, const int* __restrict__ labels,
    const float* __restrict__ tmpl_t, float* __restrict__ out) {
  const bool f32 = sniff_f32(x0);
  const int bx = blockIdx.x;           // 168 blocks: 128 | 32 | 8
  int lvl, b, tile;
  if (bx < 128)      { lvl = 0; b = bx >> 6;  tile = bx & 63; }
  else if (bx < 160) { const int l = bx - 128; lvl = 1; b = l >> 4; tile = l & 15; }
  else               { const int l = bx - 160; lvl = 2; b = l >> 2; tile = l & 3; }
  const int W = 64 >> lvl, HW = W * W;
  const int lane = threadIdx.x & 63;
  const int wv  = __builtin_amdgcn_readfirstlane(threadIdx.x >> 6); // 0..15
  const int nch = wv & 3;              // n-chunk [16nch, 16nch+16)
  const int cq  = wv >> 2;             // c-quarter [64cq, 64cq+64)
  const int p = tile * 64 + lane;
  const void* feat = (lvl == 0) ? x0 : (lvl == 1) ? x1 : x2;
  const size_t base1 = (size_t)NB * (NC + NK) * 4096;            // 2179072
  const size_t base2 = base1 + (size_t)NB * (NC + NK) * 1024;    // 2723840
  const size_t lvl_base = (lvl == 0) ? 0 : (lvl == 1) ? base1 : base2;
  float* ob = out + lvl_base + (size_t)b * (NC + NK) * HW + p;
  const size_t fb = (size_t)b * NC * HW + p;
  // this wave's tmpl rows: [c][16nch..16nch+16), stride NN per c (uniform)
  const float* tw = tmpl_t + (size_t)(lvl * NB + b) * NC * NN + 16 * nch;

  __shared__ float part[4][NN][64];    // 64 KiB: [cq][n][px]
  __shared__ float kmb[4][NK][64];     // 10 KiB: [nch][k][px]
  __shared__ int   lab[NN];
  if (threadIdx.x < NN) {
    const bool i64 = (labels[1] == 0);
    const int  m   = b * NN + threadIdx.x;
    lab[threadIdx.x] = i64 ? labels[2 * m] : labels[m];
  }
  __syncthreads();

  float acc[16];
#pragma unroll
  for (int i = 0; i < 16; ++i) acc[i] = 0.f;

  const int c0 = cq * 64;
  auto kloop = [&](auto* pf) {
    float fpre[4];                     // depth-4 feat prefetch (VGPR)
    float tb[4][16];                   // depth-4 tmpl prefetch (SGPR hoped)
#pragma unroll
    for (int k = 0; k < 4; ++k) {
      fpre[k] = (float)pf[fb + (size_t)(c0 + k) * HW];
#pragma unroll
      for (int j = 0; j < 16; ++j) tb[k][j] = tw[(size_t)(c0 + k) * NN + j];
    }
    for (int g = 0; g < 16; ++g) {     // 4 c per group, stages unrolled
#pragma unroll
      for (int st = 0; st < 4; ++st) {
        const int c = c0 + 4 * g + st;
        const float f = fpre[st];
        const int cn = min(c + 4, NC - 1);         // clamp: no OOB
        fpre[st] = (float)pf[fb + (size_t)cn * HW];          // refill feat
        if (nch == 0) ob[(size_t)c * HW] = f;      // pass-through, once per c
#pragma unroll
        for (int j = 0; j < 16; ++j) acc[j] += tb[st][j] * f;
#pragma unroll
        for (int j = 0; j < 16; ++j)               // refill tmpl, dist = 4 c
          tb[st][j] = tw[(size_t)cn * NN + j];
      }
    }
  };
  if (f32) kloop((const float*)feat);
  else     kloop((const __hip_bfloat16*)feat);

#pragma unroll
  for (int i = 0; i < 16; ++i) part[cq][16 * nch + i][lane] = acc[i];
  __syncthreads();

  // waves with cq==0: sum c-quarters for their n-chunk, class-max over 16 n
  if (cq == 0) {
    float km[NK];
#pragma unroll
    for (int k = 0; k < NK; ++k) km[k] = -FLT_MAX;
#pragma unroll
    for (int i = 0; i < 16; ++i) {
      const int n = 16 * nch + i;
      const float tot = part[0][n][lane] + part[1][n][lane]
                      + part[2][n][lane] + part[3][n][lane];
      const int L = lab[n];
#pragma unroll
      for (int kk = 1; kk <= NK; ++kk)
        if (L == kk) km[kk - 1] = fmaxf(km[kk - 1], tot);
    }
#pragma unroll
    for (int k = 0; k < NK; ++k) kmb[nch][k][lane] = km[k];
  }
  __syncthreads();

  if (wv == 0) {
#pragma unroll
    for (int k = 0; k < NK; ++k) {
      const float m = fmaxf(fmaxf(kmb[0][k][lane], kmb[1][k][lane]),
                            fmaxf(kmb[2][k][lane], kmb[3][k][lane]));
      ob[(size_t)(NC + k) * HW] = (m == -FLT_MAX) ? 0.f : m;   // absent -> 0
    }
  }
}

extern "C" void kernel_launch(void* const* d_in, const int* in_sizes, int n_in,
                              void* d_out, int out_size, void* d_ws, size_t ws_size,
                              hipStream_t stream) {
  const void* x0 = d_in[0];
  const void* x1 = d_in[1];
  const void* x2 = d_in[2];
  const void* ce = d_in[3];
  const int* idxp   = (const int*)d_in[4];
  const int* labels = (const int*)d_in[5];
  float* tmpl = (float*)d_ws;                        // 384 KiB
  float* out  = (float*)d_out;

  tmpl_kernel<<<3 * NB * NN, 256, 0, stream>>>(x0, x1, x2, ce, idxp, labels, tmpl);
  cor_kernel<<<168, 1024, 0, stream>>>(x0, x1, x2, labels, tmpl, out);
}

// Round 9
// 103.974 us; speedup vs baseline: 1.0952x; 1.0952x over previous
//
#include <hip/hip_runtime.h>
#include <hip/hip_bf16.h>
#include <cfloat>
#include <cmath>

namespace {
constexpr int NB = 2;     // batch
constexpr int NN = 64;    // user inputs
constexpr int NC = 256;   // feature channels
constexpr int NK = 10;    // classes
constexpr float ALPHA = -1.0f / 18.0f;   // -0.5/sigma^2, sigma=3
constexpr int TMPL_FLOATS = 3 * NB * NC * NN;  // 98304 floats = 384 KiB
} // namespace

// Wave-uniform fp32-vs-bf16 sniff on x0's first 2KB. fp32 low halves are
// ~uniform bits -> bf16-exp>=137 (|v|>=1024/inf/NaN) appears w.p. ~1;
// bf16 N(0,1) never has exp>=137.
__device__ __forceinline__ bool sniff_f32(const void* x0) {
  const ushort4 v = ((const ushort4*)x0)[threadIdx.x & 63];
  bool bad = (((v.x >> 7) & 0xFF) >= 137) | (((v.y >> 7) & 0xFF) >= 137) |
             (((v.z >> 7) & 0xFF) >= 137) | (((v.w >> 7) & 0xFF) >= 137);
  return __ballot(bad) != 0ULL;
}

// load float input element i, runtime dtype (wave-uniform f32 flag)
__device__ __forceinline__ float ldf(const void* p, size_t i, bool f32) {
  return f32 ? ((const float*)p)[i]
             : __bfloat162float(((const __hip_bfloat16*)p)[i]);
}

// ---------------------------------------------------------------------------
// Kernel 1 (unchanged; ~4us, never in top-5): per (level,b,n) template
// tmpl[c] = sum_p h[p]*feat[c,p], thread = channel, per-thread window loop.
// Output [lvl][b][c][n], n contiguous (64B-aligned rows for s_load_dwordx16).
// ---------------------------------------------------------------------------
__global__ __launch_bounds__(256) void tmpl_kernel(
    const void* __restrict__ x0, const void* __restrict__ x1,
    const void* __restrict__ x2, const void* __restrict__ centers,
    const int* __restrict__ idxp, const int* __restrict__ labels,
    float* __restrict__ tmpl_t) {
  const bool f32 = sniff_f32(x0);
  const int bx  = blockIdx.x;          // 3*NB*NN = 384 blocks
  const int lvl = bx >> 7;
  const int b   = (bx >> 6) & 1;
  const int n   = bx & 63;
  const int W   = 64 >> lvl;           // 64,32,16
  const int HW  = W * W;
  const float s = (float)(8 << lvl);   // nearest-resize stride
  const void* feat = (lvl == 0) ? x0 : (lvl == 1) ? x1 : x2;

  __shared__ float ex[64], ey[64];
  __shared__ float sh_inv;
  __shared__ int   sh_win[4];

  const int t = threadIdx.x;
  const float cx = ldf(centers, (size_t)(b * NN + n) * 2 + 0, f32);
  const float cy = ldf(centers, (size_t)(b * NN + n) * 2 + 1, f32);

  if (t < W) {
    const float dx = (float)t * s + 0.5f - cx;
    const float dy = (float)t * s + 0.5f - cy;
    ex[t] = expf(ALPHA * dx * dx);
    ey[t] = expf(ALPHA * dy * dy);
  }
  __syncthreads();

  if (t == 0) {
    const bool i64 = (labels[1] == 0);            // int64 hedge
    const int  m   = b * NN + n;
    const int  iv  = i64 ? idxp[2 * m] : idxp[m];
    float Sx = 0.f, Sy = 0.f;
    for (int i = 0; i < W; ++i) { Sx += ex[i]; Sy += ey[i]; }
    sh_inv = (iv != -1) ? 1.0f / (Sx * Sy + 1e-8f) : 0.0f;
    int cs = (int)floorf((cx - 0.5f) / s + 0.5f); cs = min(max(cs, 0), W - 1);
    int rs = (int)floorf((cy - 0.5f) / s + 0.5f); rs = min(max(rs, 0), W - 1);
    const float tx = ex[cs] * 1e-7f, ty = ey[rs] * 1e-7f;
    int clo = cs, chi = cs, rlo = rs, rhi = rs;
    while (clo > 0     && ex[clo - 1] >= tx) --clo;
    while (chi < W - 1 && ex[chi + 1] >= tx) ++chi;
    while (rlo > 0     && ey[rlo - 1] >= ty) --rlo;
    while (rhi < W - 1 && ey[rhi + 1] >= ty) ++rhi;
    sh_win[0] = clo; sh_win[1] = chi; sh_win[2] = rlo; sh_win[3] = rhi;
  }
  __syncthreads();

  const float inv = sh_inv;
  const int clo = sh_win[0], chi = sh_win[1], rlo = sh_win[2], rhi = sh_win[3];
  const size_t cbase = (size_t)(b * NC + t) * HW;   // t = channel
  float acc = 0.f;
  for (int r = rlo; r <= rhi; ++r) {
    float rowa = 0.f;
    for (int c = clo; c <= chi; ++c)
      rowa += ex[c] * ldf(feat, cbase + r * W + c, f32);
    acc += ey[r] * rowa;
  }
  tmpl_t[(((size_t)lvl * NB + b) * NC + t) * NN + n] = acc * inv;
}

// ---------------------------------------------------------------------------
// Kernel 2 (v7): block = 64-pixel tile, 1024 threads = 16 waves =
// 4 n-chunks x 4 c-quarters. R8 lesson: depth-4 uniform buffers (64 floats)
// blow the ~102-SGPR budget -> demoted to VGPRs -> regression. v7 uses a
// DEPTH-2 rotating buffer tb[2][16] (32 SGPRs, fits; R5's VGPR=24/SGPR=80
// proves the compiler scalarizes these uniform loads when they fit). One
// s_load_dwordx16 per (wave,c), 16 v_fmac with SGPR operand. Main loop has
// ZERO LDS traffic (R7's 4096 broadcast ds_read_b128 = 19us eliminated).
// Prefetch distance 2 ~= 256 cyc in flight >= ~200 cyc L2 latency.
// ---------------------------------------------------------------------------
__global__ __launch_bounds__(1024, 1) void cor_kernel(
    const void* __restrict__ x0, const void* __restrict__ x1,
    const void* __restrict__ x2, const int* __restrict__ labels,
    const float* __restrict__ tmpl_t, float* __restrict__ out) {
  const bool f32 = sniff_f32(x0);
  const int bx = blockIdx.x;           // 168 blocks: 128 | 32 | 8
  int lvl, b, tile;
  if (bx < 128)      { lvl = 0; b = bx >> 6;  tile = bx & 63; }
  else if (bx < 160) { const int l = bx - 128; lvl = 1; b = l >> 4; tile = l & 15; }
  else               { const int l = bx - 160; lvl = 2; b = l >> 2; tile = l & 3; }
  const int W = 64 >> lvl, HW = W * W;
  const int lane = threadIdx.x & 63;
  const int wv  = __builtin_amdgcn_readfirstlane(threadIdx.x >> 6); // 0..15
  const int nch = wv & 3;              // n-chunk [16nch, 16nch+16)
  const int cq  = wv >> 2;             // c-quarter [64cq, 64cq+64)
  const int p = tile * 64 + lane;
  const void* feat = (lvl == 0) ? x0 : (lvl == 1) ? x1 : x2;
  const size_t base1 = (size_t)NB * (NC + NK) * 4096;            // 2179072
  const size_t base2 = base1 + (size_t)NB * (NC + NK) * 1024;    // 2723840
  const size_t lvl_base = (lvl == 0) ? 0 : (lvl == 1) ? base1 : base2;
  float* ob = out + lvl_base + (size_t)b * (NC + NK) * HW + p;
  const size_t fb = (size_t)b * NC * HW + p;
  // this wave's tmpl rows: [c][16nch..16nch+16), stride NN per c (uniform,
  // 64B-aligned -> s_load_dwordx16)
  const float* tw = tmpl_t + (size_t)(lvl * NB + b) * NC * NN + 16 * nch;

  __shared__ float part[4][NN][64];    // 64 KiB: [cq][n][px]
  __shared__ float kmb[4][NK][64];     // 10 KiB: [nch][k][px]
  __shared__ int   lab[NN];
  if (threadIdx.x < NN) {
    const bool i64 = (labels[1] == 0);
    const int  m   = b * NN + threadIdx.x;
    lab[threadIdx.x] = i64 ? labels[2 * m] : labels[m];
  }
  __syncthreads();

  float acc[16];
#pragma unroll
  for (int i = 0; i < 16; ++i) acc[i] = 0.f;

  const int c0 = cq * 64;
  auto kloop = [&](auto* pf) {
    float fpre[4];                     // depth-4 feat prefetch (VGPR)
    float tb[2][16];                   // depth-2 tmpl buffer (32 SGPRs)
#pragma unroll
    for (int k = 0; k < 4; ++k)
      fpre[k] = (float)pf[fb + (size_t)(c0 + k) * HW];
#pragma unroll
    for (int k = 0; k < 2; ++k)
#pragma unroll
      for (int j = 0; j < 16; ++j)
        tb[k][j] = tw[(size_t)(c0 + k) * NN + j];
#pragma unroll 4
    for (int i = 0; i < 64; ++i) {
      const int c = c0 + i;
      const float f = fpre[i & 3];
      const int cf = min(c + 4, NC - 1);           // clamp: no OOB
      fpre[i & 3] = (float)pf[fb + (size_t)cf * HW];         // refill feat
      if (nch == 0) ob[(size_t)c * HW] = f;        // pass-through, once per c
#pragma unroll
      for (int j = 0; j < 16; ++j) acc[j] += tb[i & 1][j] * f;
      const int ct = min(c + 2, NC - 1);           // refill tmpl, dist = 2
#pragma unroll
      for (int j = 0; j < 16; ++j) tb[i & 1][j] = tw[(size_t)ct * NN + j];
    }
  };
  if (f32) kloop((const float*)feat);
  else     kloop((const __hip_bfloat16*)feat);

#pragma unroll
  for (int i = 0; i < 16; ++i) part[cq][16 * nch + i][lane] = acc[i];
  __syncthreads();

  // waves with cq==0: sum c-quarters for their n-chunk, class-max over 16 n
  if (cq == 0) {
    float km[NK];
#pragma unroll
    for (int k = 0; k < NK; ++k) km[k] = -FLT_MAX;
#pragma unroll
    for (int i = 0; i < 16; ++i) {
      const int n = 16 * nch + i;
      const float tot = part[0][n][lane] + part[1][n][lane]
                      + part[2][n][lane] + part[3][n][lane];
      const int L = lab[n];
#pragma unroll
      for (int kk = 1; kk <= NK; ++kk)
        if (L == kk) km[kk - 1] = fmaxf(km[kk - 1], tot);
    }
#pragma unroll
    for (int k = 0; k < NK; ++k) kmb[nch][k][lane] = km[k];
  }
  __syncthreads();

  if (wv == 0) {
#pragma unroll
    for (int k = 0; k < NK; ++k) {
      const float m = fmaxf(fmaxf(kmb[0][k][lane], kmb[1][k][lane]),
                            fmaxf(kmb[2][k][lane], kmb[3][k][lane]));
      ob[(size_t)(NC + k) * HW] = (m == -FLT_MAX) ? 0.f : m;   // absent -> 0
    }
  }
}

extern "C" void kernel_launch(void* const* d_in, const int* in_sizes, int n_in,
                              void* d_out, int out_size, void* d_ws, size_t ws_size,
                              hipStream_t stream) {
  const void* x0 = d_in[0];
  const void* x1 = d_in[1];
  const void* x2 = d_in[2];
  const void* ce = d_in[3];
  const int* idxp   = (const int*)d_in[4];
  const int* labels = (const int*)d_in[5];
  float* tmpl = (float*)d_ws;                        // 384 KiB
  float* out  = (float*)d_out;

  tmpl_kernel<<<3 * NB * NN, 256, 0, stream>>>(x0, x1, x2, ce, idxp, labels, tmpl);
  cor_kernel<<<168, 1024, 0, stream>>>(x0, x1, x2, labels, tmpl, out);
}